// Round 2
// baseline (784.143 us; speedup 1.0000x reference)
//
#include <hip/hip_runtime.h>
#include <hip/hip_bf16.h>
#include <stdint.h>

#define BATCH  4096
#define INPUT  4096
#define HIDDEN 4096
#define OUTPUT 1024
#define KCAT   (INPUT + HIDDEN)   // 8192

typedef __bf16 bf16x8 __attribute__((ext_vector_type(8)));
typedef float  f32x4  __attribute__((ext_vector_type(4)));

// round-to-nearest-even f32 -> bf16
__device__ __forceinline__ uint16_t f2bf(float f) {
  uint32_t u = __builtin_bit_cast(uint32_t, f);
  u += 0x7fffu + ((u >> 16) & 1u);
  return (uint16_t)(u >> 16);
}

__device__ __forceinline__ void gll16(const void* g, void* l) {
  __builtin_amdgcn_global_load_lds(
      (const __attribute__((address_space(1))) void*)g,
      (__attribute__((address_space(3))) void*)l, 16, 0, 0);
}

// Convert f32 -> bf16 with optional row-wise concat of two sources.
// dst is rows x ctot; cols [0,c0) from s0 (row stride c0), cols [c0,ctot) from s1.
// Each thread handles 8 consecutive dst elements (never straddles the seam:
// c0 and ctot are multiples of 8).
__global__ void cvt_concat(const float* __restrict__ s0, const float* __restrict__ s1,
                           uint16_t* __restrict__ dst, int c0, int ctot, int n8) {
  int i = blockIdx.x * blockDim.x + threadIdx.x;
  if (i >= n8) return;
  long e = (long)i * 8;
  int  col = (int)(e % ctot);
  long row = e / ctot;
  const float* src = (col < c0) ? (s0 + row * (long)c0 + col)
                                : (s1 + row * (long)(ctot - c0) + (col - c0));
  const float4 f0 = reinterpret_cast<const float4*>(src)[0];
  const float4 f1 = reinterpret_cast<const float4*>(src)[1];
  uint4 o;
  o.x = (uint32_t)f2bf(f0.x) | ((uint32_t)f2bf(f0.y) << 16);
  o.y = (uint32_t)f2bf(f0.z) | ((uint32_t)f2bf(f0.w) << 16);
  o.z = (uint32_t)f2bf(f1.x) | ((uint32_t)f2bf(f1.y) << 16);
  o.w = (uint32_t)f2bf(f1.z) | ((uint32_t)f2bf(f1.w) << 16);
  *reinterpret_cast<uint4*>(dst + e) = o;
}

// C = A @ Bm^T (+bias, epilogue), A: MxK bf16 row-major, Bm: NxK bf16 row-major.
// 128x128 tile, 4 waves (2x2 of 64x64), BK=32, mfma_f32_16x16x32_bf16.
// EPI==0: C[r][c] = tanh(acc + bias[c]) stored bf16; EPI==1: f32 store acc + bias[c].
template<int EPI>
__global__ __launch_bounds__(256)
void gemm_bt(const uint16_t* __restrict__ A, const uint16_t* __restrict__ Bm,
             const float* __restrict__ bias, void* __restrict__ Cout,
             int N, int K) {
  __shared__ __align__(16) uint16_t sA[128 * 32];
  __shared__ __align__(16) uint16_t sB[128 * 32];

  const int tid  = threadIdx.x;
  const int lane = tid & 63;
  const int wave = tid >> 6;
  const int wm = wave >> 1, wn = wave & 1;
  const int m0 = blockIdx.y * 128;
  const int n0 = blockIdx.x * 128;

  f32x4 acc[4][4];
#pragma unroll
  for (int m = 0; m < 4; ++m)
#pragma unroll
    for (int n = 0; n < 4; ++n) acc[m][n] = (f32x4)(0.0f);

  // staging: chunk c (16B = 8 bf16) covers tile-row c>>2, k-chunk c&3.
  // thread stages chunks {tid, tid+256}; LDS dst is linear (wave-uniform base + lane*16).
  const int r0  = tid >> 2;
  const int kc0 = tid & 3;
  const uint16_t* gA = A + (long)(m0 + r0) * K + kc0 * 8;
  const uint16_t* gB = Bm + (long)(n0 + r0) * K + kc0 * 8;
  const long rstep = 64L * K;                 // +64 rows for second chunk
  uint16_t* lA = &sA[tid * 8];
  uint16_t* lB = &sB[tid * 8];

  const int ko = (lane >> 4) * 8;             // fragment k-offset
  const int fr = lane & 15;                   // fragment row/col within 16

  for (int k0 = 0; k0 < K; k0 += 32) {
    gll16(gA + k0,         lA);
    gll16(gA + k0 + rstep, lA + 2048);
    gll16(gB + k0,         lB);
    gll16(gB + k0 + rstep, lB + 2048);
    __syncthreads();   // compiler drains vmcnt before s_barrier

    bf16x8 af[4], bf_[4];
#pragma unroll
    for (int m = 0; m < 4; ++m) {
      af[m]  = *reinterpret_cast<const bf16x8*>(&sA[(wm * 64 + m * 16 + fr) * 32 + ko]);
      bf_[m] = *reinterpret_cast<const bf16x8*>(&sB[(wn * 64 + m * 16 + fr) * 32 + ko]);
    }
#pragma unroll
    for (int m = 0; m < 4; ++m)
#pragma unroll
      for (int n = 0; n < 4; ++n)
        acc[m][n] = __builtin_amdgcn_mfma_f32_16x16x32_bf16(af[m], bf_[n], acc[m][n], 0, 0, 0);
    __syncthreads();
  }

  // epilogue: C/D layout col=lane&15, row=(lane>>4)*4+reg  [m89/m91 verified]
  const int rbase = m0 + wm * 64 + (lane >> 4) * 4;
  const int cbase = n0 + wn * 64 + fr;
#pragma unroll
  for (int n = 0; n < 4; ++n) {
    const int col = cbase + n * 16;
    const float bv = bias[col];
#pragma unroll
    for (int m = 0; m < 4; ++m) {
#pragma unroll
      for (int r = 0; r < 4; ++r) {
        const int row = rbase + m * 16 + r;
        const float v = acc[m][n][r] + bv;
        if (EPI == 0) {
          ((uint16_t*)Cout)[(long)row * N + col] = f2bf(tanhf(v));
        } else {
          ((float*)Cout)[(long)row * N + col] = v;
        }
      }
    }
  }
}

extern "C" void kernel_launch(void* const* d_in, const int* in_sizes, int n_in,
                              void* d_out, int out_size, void* d_ws, size_t ws_size,
                              hipStream_t stream) {
  const float* x    = (const float*)d_in[0];
  const float* h    = (const float*)d_in[1];
  const float* Wx   = (const float*)d_in[2];
  const float* Wh   = (const float*)d_in[3];
  const float* B    = (const float*)d_in[4];
  const float* Wout = (const float*)d_in[5];
  const float* Bout = (const float*)d_in[6];
  float* out = (float*)d_out;

  // workspace layout (bf16): A_cat | W_cat | Wout_bf | Hnew  = ~168 MiB
  uint16_t* Acat  = (uint16_t*)d_ws;
  uint16_t* Wcat  = Acat  + (size_t)BATCH  * KCAT;
  uint16_t* WoutB = Wcat  + (size_t)HIDDEN * KCAT;
  uint16_t* Hnew  = WoutB + (size_t)OUTPUT * HIDDEN;

  const int n8A = BATCH  * KCAT / 8;     // 4,194,304
  const int n8W = HIDDEN * KCAT / 8;     // 4,194,304
  const int n8O = OUTPUT * HIDDEN / 8;   //   524,288

  cvt_concat<<<(n8A + 255) / 256, 256, 0, stream>>>(x,  h,  Acat,  INPUT,  KCAT,   n8A);
  cvt_concat<<<(n8W + 255) / 256, 256, 0, stream>>>(Wx, Wh, Wcat,  INPUT,  KCAT,   n8W);
  cvt_concat<<<(n8O + 255) / 256, 256, 0, stream>>>(Wout, Wout, WoutB, HIDDEN, HIDDEN, n8O);

  // GEMM1: Hnew = tanh(A_cat @ W_cat^T + B)   (4096x4096, K=8192)
  gemm_bt<0><<<dim3(HIDDEN / 128, BATCH / 128), 256, 0, stream>>>(
      Acat, Wcat, B, (void*)Hnew, HIDDEN, KCAT);

  // GEMM2: out = Hnew @ Wout^T + Bout         (4096x1024, K=4096)
  gemm_bt<1><<<dim3(OUTPUT / 128, BATCH / 128), 256, 0, stream>>>(
      Hnew, WoutB, Bout, (void*)out, OUTPUT, HIDDEN);
}

// Round 6
// 613.838 us; speedup vs baseline: 1.2774x; 1.2774x over previous
//
#include <hip/hip_runtime.h>
#include <hip/hip_bf16.h>
#include <stdint.h>

#define BATCH  4096
#define INPUT  4096
#define HIDDEN 4096
#define OUTPUT 1024
#define KCAT   (INPUT + HIDDEN)   // 8192

typedef __bf16 bf16x8 __attribute__((ext_vector_type(8)));
typedef float  f32x4  __attribute__((ext_vector_type(4)));

// round-to-nearest-even f32 -> bf16
__device__ __forceinline__ uint16_t f2bf(float f) {
  uint32_t u = __builtin_bit_cast(uint32_t, f);
  u += 0x7fffu + ((u >> 16) & 1u);
  return (uint16_t)(u >> 16);
}

__device__ __forceinline__ void gll16(const void* g, void* l) {
  __builtin_amdgcn_global_load_lds(
      (const __attribute__((address_space(1))) void*)g,
      (__attribute__((address_space(3))) void*)l, 16, 0, 0);
}

// f32 -> bf16 with row-wise concat of two sources.
__global__ void cvt_concat(const float* __restrict__ s0, const float* __restrict__ s1,
                           uint16_t* __restrict__ dst, int c0, int ctot, int n8) {
  int i = blockIdx.x * blockDim.x + threadIdx.x;
  if (i >= n8) return;
  long e = (long)i * 8;
  int  col = (int)(e % ctot);
  long row = e / ctot;
  const float* src = (col < c0) ? (s0 + row * (long)c0 + col)
                                : (s1 + row * (long)(ctot - c0) + (col - c0));
  const float4 f0 = reinterpret_cast<const float4*>(src)[0];
  const float4 f1 = reinterpret_cast<const float4*>(src)[1];
  uint4 o;
  o.x = (uint32_t)f2bf(f0.x) | ((uint32_t)f2bf(f0.y) << 16);
  o.y = (uint32_t)f2bf(f0.z) | ((uint32_t)f2bf(f0.w) << 16);
  o.z = (uint32_t)f2bf(f1.x) | ((uint32_t)f2bf(f1.y) << 16);
  o.w = (uint32_t)f2bf(f1.z) | ((uint32_t)f2bf(f1.w) << 16);
  *reinterpret_cast<uint4*>(dst + e) = o;
}

// ---------- 128x128-tile kernel (kept for GEMM2, verified round 2) ----------
template<int EPI>
__global__ __launch_bounds__(256)
void gemm_bt(const uint16_t* __restrict__ A, const uint16_t* __restrict__ Bm,
             const float* __restrict__ bias, void* __restrict__ Cout,
             int N, int K) {
  __shared__ __align__(16) uint16_t sA[128 * 32];
  __shared__ __align__(16) uint16_t sB[128 * 32];

  const int tid  = threadIdx.x;
  const int lane = tid & 63;
  const int wave = tid >> 6;
  const int wm = wave >> 1, wn = wave & 1;
  const int m0 = blockIdx.y * 128;
  const int n0 = blockIdx.x * 128;

  f32x4 acc[4][4];
#pragma unroll
  for (int m = 0; m < 4; ++m)
#pragma unroll
    for (int n = 0; n < 4; ++n) acc[m][n] = (f32x4)(0.0f);

  const int r0  = tid >> 2;
  const int kc0 = tid & 3;
  const uint16_t* gA = A + (long)(m0 + r0) * K + kc0 * 8;
  const uint16_t* gB = Bm + (long)(n0 + r0) * K + kc0 * 8;
  const long rstep = 64L * K;
  uint16_t* lA = &sA[tid * 8];
  uint16_t* lB = &sB[tid * 8];

  const int ko = (lane >> 4) * 8;
  const int fr = lane & 15;

  for (int k0 = 0; k0 < K; k0 += 32) {
    gll16(gA + k0,         lA);
    gll16(gA + k0 + rstep, lA + 2048);
    gll16(gB + k0,         lB);
    gll16(gB + k0 + rstep, lB + 2048);
    __syncthreads();

    bf16x8 af[4], bf_[4];
#pragma unroll
    for (int m = 0; m < 4; ++m) {
      af[m]  = *reinterpret_cast<const bf16x8*>(&sA[(wm * 64 + m * 16 + fr) * 32 + ko]);
      bf_[m] = *reinterpret_cast<const bf16x8*>(&sB[(wn * 64 + m * 16 + fr) * 32 + ko]);
    }
#pragma unroll
    for (int m = 0; m < 4; ++m)
#pragma unroll
      for (int n = 0; n < 4; ++n)
        acc[m][n] = __builtin_amdgcn_mfma_f32_16x16x32_bf16(af[m], bf_[n], acc[m][n], 0, 0, 0);
    __syncthreads();
  }

  const int rbase = m0 + wm * 64 + (lane >> 4) * 4;
  const int cbase = n0 + wn * 64 + fr;
#pragma unroll
  for (int n = 0; n < 4; ++n) {
    const int col = cbase + n * 16;
    const float bv = bias[col];
#pragma unroll
    for (int m = 0; m < 4; ++m) {
#pragma unroll
      for (int r = 0; r < 4; ++r) {
        const int row = rbase + m * 16 + r;
        const float v = acc[m][n][r] + bv;
        if (EPI == 0) {
          ((uint16_t*)Cout)[(long)row * N + col] = f2bf(tanhf(v));
        } else {
          ((float*)Cout)[(long)row * N + col] = v;
        }
      }
    }
  }
}

// ---------- 256x256-tile, BK=64, 8-wave, 4-phase pipelined kernel (GEMM1) ----------
// LDS: 2 buffers x (A 256x64 + B 256x64) bf16 = 128 KiB -> 1 block/CU.
// Staging groups (quadrant-aligned, 2 gll16/thread each):
//   A-G0 = rows {0-63,128-191}   (read by phases 1,2)   A-G1 = +64  (phases 3,4)
//   B-H0 = rows {0-31,64-95,128-159,192-223} (phases 1,3)  B-H1 = +32 (phases 2,4)
// Stage schedule per tile t: p1:A-G1(t+1)->nxt  p2:B-H1(t+1)->nxt
//                            p3:A-G0(t+2)->cur  p4:B-H0(t+2)->cur
//   (cur regions are dead by then: G0 reads only at top of p1; H0 reads done by p3's MFMA wait)
// Visibility: vmcnt(6)+barrier each phase => groups issued >=3 phases ago are in LDS;
//   every consume distance is >=4 phases. Prologue: 12 loads, vmcnt(4) lands tile 0.
// Bank conflicts: physical 16B-chunk = row*8 + (c ^ (row&7)), applied to the global
//   source on stage (gload_lds dst linear) and to the ds_read address. Each 8-lane
//   subgroup covers all 8 chunk-slots -> conflict-free.
__global__ __launch_bounds__(512, 2)
void gemm256_8ph(const uint16_t* __restrict__ A, const uint16_t* __restrict__ Bm,
                 const float* __restrict__ bias, uint16_t* __restrict__ C,
                 int N, int K) {
  __shared__ __align__(16) uint16_t sA[2][256 * 64];
  __shared__ __align__(16) uint16_t sB[2][256 * 64];

  const int tid  = threadIdx.x;
  const int lane = tid & 63;
  const int wave = tid >> 6;
  const int wm = wave >> 2, wn = wave & 3;      // 2M x 4N waves
  const int fr = lane & 15, g4 = lane >> 4;

  // bijective XCD-chunked swizzle (gridDim.x % 8 == 0)
  const int nwg = gridDim.x;
  const int bid = blockIdx.x;
  const int wg  = (bid & 7) * (nwg >> 3) + (bid >> 3);
  const int ntn = N >> 8;
  const int tm = wg / ntn, tn = wg % ntn;
  const long m0 = (long)tm << 8, n0 = (long)tn << 8;

  const uint16_t* Ag = A  + m0 * K;
  const uint16_t* Bg = Bm + n0 * K;
  const int NT = K >> 6;

  f32x4 acc[8][4];
#pragma unroll
  for (int i = 0; i < 8; ++i)
#pragma unroll
    for (int j = 0; j < 4; ++j) acc[i][j] = (f32x4)(0.0f);

  auto stA = [&](int b, int g, int k0) {
#pragma unroll
    for (int i = 0; i < 2; ++i) {
      int p   = g * 512 + i * 1024 + tid;          // physical chunk
      int row = p >> 3;
      int lc  = (p & 7) ^ (row & 7);               // logical k-chunk (inverse swizzle)
      gll16(Ag + (long)row * K + k0 + lc * 8, &sA[b][p * 8]);
    }
  };
  auto stB = [&](int b, int g, int k0) {
#pragma unroll
    for (int i = 0; i < 2; ++i) {
      int c   = i * 512 + tid;
      int p   = c + ((c >> 8) << 8) + (g ? 256 : 0);
      int row = p >> 3;
      int lc  = (p & 7) ^ (row & 7);
      gll16(Bg + (long)row * K + k0 + lc * 8, &sB[b][p * 8]);
    }
  };

  // prologue: tile 0 complete + G0/H0 of tile 1 in flight
  stA(0, 0, 0); stB(0, 0, 0); stA(0, 1, 0); stB(0, 1, 0);
  stA(1, 0, 64); stB(1, 0, 64);
  asm volatile("s_waitcnt vmcnt(4)" ::: "memory");
  __builtin_amdgcn_s_barrier();

  const int xk0 = ((0 + g4) ^ (fr & 7)) << 3;      // swizzled elem offset, kk=0
  const int xk1 = ((4 + g4) ^ (fr & 7)) << 3;      // kk=1

  int cur = 0;
  for (int t = 0; t < NT; ++t) {
    const int k1 = (t + 1) << 6, k2 = (t + 2) << 6;
    const int nb = cur ^ 1;
    const uint16_t* sAc = &sA[cur][0];
    const uint16_t* sBc = &sB[cur][0];
    bf16x8 ah[4][2], bh[2][2];

    // ---- phase 1: quadrant (qm=0, qn=0) ----
#pragma unroll
    for (int m = 0; m < 4; ++m) {
      const int ra = (wm * 128 + m * 16 + fr) * 64;
      ah[m][0] = *reinterpret_cast<const bf16x8*>(&sAc[ra + xk0]);
      ah[m][1] = *reinterpret_cast<const bf16x8*>(&sAc[ra + xk1]);
    }
#pragma unroll
    for (int n = 0; n < 2; ++n) {
      const int rb = (wn * 64 + n * 16 + fr) * 64;
      bh[n][0] = *reinterpret_cast<const bf16x8*>(&sBc[rb + xk0]);
      bh[n][1] = *reinterpret_cast<const bf16x8*>(&sBc[rb + xk1]);
    }
    if (t + 1 < NT) stA(nb, 1, k1);
    asm volatile("s_waitcnt vmcnt(6)" ::: "memory");
    __builtin_amdgcn_s_barrier();
    __builtin_amdgcn_s_setprio(1);
#pragma unroll
    for (int m = 0; m < 4; ++m)
#pragma unroll
      for (int n = 0; n < 2; ++n) {
        acc[m][n] = __builtin_amdgcn_mfma_f32_16x16x32_bf16(ah[m][0], bh[n][0], acc[m][n], 0, 0, 0);
        acc[m][n] = __builtin_amdgcn_mfma_f32_16x16x32_bf16(ah[m][1], bh[n][1], acc[m][n], 0, 0, 0);
      }
    __builtin_amdgcn_s_setprio(0);
    __builtin_amdgcn_s_barrier();

    // ---- phase 2: quadrant (0,1) — reuse ah ----
#pragma unroll
    for (int n = 0; n < 2; ++n) {
      const int rb = (wn * 64 + (n + 2) * 16 + fr) * 64;
      bh[n][0] = *reinterpret_cast<const bf16x8*>(&sBc[rb + xk0]);
      bh[n][1] = *reinterpret_cast<const bf16x8*>(&sBc[rb + xk1]);
    }
    if (t + 1 < NT) stB(nb, 1, k1);
    asm volatile("s_waitcnt vmcnt(6)" ::: "memory");
    __builtin_amdgcn_s_barrier();
    __builtin_amdgcn_s_setprio(1);
#pragma unroll
    for (int m = 0; m < 4; ++m)
#pragma unroll
      for (int n = 0; n < 2; ++n) {
        acc[m][n + 2] = __builtin_amdgcn_mfma_f32_16x16x32_bf16(ah[m][0], bh[n][0], acc[m][n + 2], 0, 0, 0);
        acc[m][n + 2] = __builtin_amdgcn_mfma_f32_16x16x32_bf16(ah[m][1], bh[n][1], acc[m][n + 2], 0, 0, 0);
      }
    __builtin_amdgcn_s_setprio(0);
    __builtin_amdgcn_s_barrier();

    // ---- phase 3: quadrant (1,0) ----
#pragma unroll
    for (int m = 0; m < 4; ++m) {
      const int ra = (wm * 128 + (m + 4) * 16 + fr) * 64;
      ah[m][0] = *reinterpret_cast<const bf16x8*>(&sAc[ra + xk0]);
      ah[m][1] = *reinterpret_cast<const bf16x8*>(&sAc[ra + xk1]);
    }
#pragma unroll
    for (int n = 0; n < 2; ++n) {
      const int rb = (wn * 64 + n * 16 + fr) * 64;
      bh[n][0] = *reinterpret_cast<const bf16x8*>(&sBc[rb + xk0]);
      bh[n][1] = *reinterpret_cast<const bf16x8*>(&sBc[rb + xk1]);
    }
    if (t + 2 < NT) stA(cur, 0, k2);
    asm volatile("s_waitcnt vmcnt(6)" ::: "memory");
    __builtin_amdgcn_s_barrier();
    __builtin_amdgcn_s_setprio(1);
#pragma unroll
    for (int m = 0; m < 4; ++m)
#pragma unroll
      for (int n = 0; n < 2; ++n) {
        acc[m + 4][n] = __builtin_amdgcn_mfma_f32_16x16x32_bf16(ah[m][0], bh[n][0], acc[m + 4][n], 0, 0, 0);
        acc[m + 4][n] = __builtin_amdgcn_mfma_f32_16x16x32_bf16(ah[m][1], bh[n][1], acc[m + 4][n], 0, 0, 0);
      }
    __builtin_amdgcn_s_setprio(0);
    __builtin_amdgcn_s_barrier();

    // ---- phase 4: quadrant (1,1) — reuse ah ----
#pragma unroll
    for (int n = 0; n < 2; ++n) {
      const int rb = (wn * 64 + (n + 2) * 16 + fr) * 64;
      bh[n][0] = *reinterpret_cast<const bf16x8*>(&sBc[rb + xk0]);
      bh[n][1] = *reinterpret_cast<const bf16x8*>(&sBc[rb + xk1]);
    }
    if (t + 2 < NT) stB(cur, 0, k2);
    asm volatile("s_waitcnt vmcnt(6)" ::: "memory");
    __builtin_amdgcn_s_barrier();
    __builtin_amdgcn_s_setprio(1);
#pragma unroll
    for (int m = 0; m < 4; ++m)
#pragma unroll
      for (int n = 0; n < 2; ++n) {
        acc[m + 4][n + 2] = __builtin_amdgcn_mfma_f32_16x16x32_bf16(ah[m][0], bh[n][0], acc[m + 4][n + 2], 0, 0, 0);
        acc[m + 4][n + 2] = __builtin_amdgcn_mfma_f32_16x16x32_bf16(ah[m][1], bh[n][1], acc[m + 4][n + 2], 0, 0, 0);
      }
    __builtin_amdgcn_s_setprio(0);
    __builtin_amdgcn_s_barrier();

    cur ^= 1;
  }

  // epilogue: C/D layout col=lane&15, row=(lane>>4)*4+reg
  const long rbase = m0 + wm * 128 + g4 * 4;
  const long cbase = n0 + wn * 64 + fr;
#pragma unroll
  for (int n = 0; n < 4; ++n) {
    const long col = cbase + n * 16;
    const float bv = bias[col];
#pragma unroll
    for (int m = 0; m < 8; ++m) {
#pragma unroll
      for (int r = 0; r < 4; ++r) {
        const long row = rbase + m * 16 + r;
        C[row * N + col] = f2bf(tanhf(acc[m][n][r] + bv));
      }
    }
  }
}

extern "C" void kernel_launch(void* const* d_in, const int* in_sizes, int n_in,
                              void* d_out, int out_size, void* d_ws, size_t ws_size,
                              hipStream_t stream) {
  const float* x    = (const float*)d_in[0];
  const float* h    = (const float*)d_in[1];
  const float* Wx   = (const float*)d_in[2];
  const float* Wh   = (const float*)d_in[3];
  const float* B    = (const float*)d_in[4];
  const float* Wout = (const float*)d_in[5];
  const float* Bout = (const float*)d_in[6];
  float* out = (float*)d_out;

  uint16_t* Acat  = (uint16_t*)d_ws;
  uint16_t* Wcat  = Acat  + (size_t)BATCH  * KCAT;
  uint16_t* WoutB = Wcat  + (size_t)HIDDEN * KCAT;
  uint16_t* Hnew  = WoutB + (size_t)OUTPUT * HIDDEN;

  const int n8A = BATCH  * KCAT / 8;
  const int n8W = HIDDEN * KCAT / 8;
  const int n8O = OUTPUT * HIDDEN / 8;

  cvt_concat<<<(n8A + 255) / 256, 256, 0, stream>>>(x,  h,  Acat,  INPUT,  KCAT,   n8A);
  cvt_concat<<<(n8W + 255) / 256, 256, 0, stream>>>(Wx, Wh, Wcat,  INPUT,  KCAT,   n8W);
  cvt_concat<<<(n8O + 255) / 256, 256, 0, stream>>>(Wout, Wout, WoutB, HIDDEN, HIDDEN, n8O);

  // GEMM1: Hnew = tanh(A_cat @ W_cat^T + B)  — 256² 8-wave pipelined kernel
  gemm256_8ph<<<dim3((BATCH / 256) * (HIDDEN / 256)), 512, 0, stream>>>(
      Acat, Wcat, B, Hnew, HIDDEN, KCAT);

  // GEMM2: out = Hnew @ Wout^T + Bout — 128² kernel (N=1024 would give only 64 blocks at 256²)
  gemm_bt<1><<<dim3(OUTPUT / 128, BATCH / 128), 256, 0, stream>>>(
      Hnew, WoutB, Bout, (void*)out, OUTPUT, HIDDEN);
}